// Round 2
// baseline (515.249 us; speedup 1.0000x reference)
//
#include <hip/hip_runtime.h>

#define B_ 8
#define C_ 128
#define MIP_ 32
#define L_ 65536
#define ROWS_ (B_ * C_)      // 1024
#define L4_ (L_ / 4)         // 16384
#define BN_EPS_ 1e-5f

// ---------------------------------------------------------------------------
// Kernel 1: per-(b,c) row mean. One block per row, 256 threads, float4 loads.
// ---------------------------------------------------------------------------
__global__ __launch_bounds__(256) void reduce_rows(const float* __restrict__ x,
                                                   float* __restrict__ avg) {
    const int row = blockIdx.x;
    const float4* __restrict__ xr = (const float4*)(x + (size_t)row * L_);
    float s = 0.0f;
    for (int i = threadIdx.x; i < L4_; i += 256) {
        float4 v = xr[i];
        s += (v.x + v.y) + (v.z + v.w);
    }
    // wave (64-lane) reduce
    #pragma unroll
    for (int off = 32; off > 0; off >>= 1) s += __shfl_down(s, off);
    __shared__ float ls[4];
    if ((threadIdx.x & 63) == 0) ls[threadIdx.x >> 6] = s;
    __syncthreads();
    if (threadIdx.x == 0) {
        float t = (ls[0] + ls[1]) + (ls[2] + ls[3]);
        avg[row] = t * (1.0f / (float)L_);
    }
}

// ---------------------------------------------------------------------------
// Kernel 2: tiny FC stack -> thres[b*C + c]. Single block, 256 threads.
// ---------------------------------------------------------------------------
__global__ __launch_bounds__(256) void fc_thres(const float* __restrict__ avg,
                                                const float* __restrict__ w1,
                                                const float* __restrict__ b1,
                                                const float* __restrict__ gamma,
                                                const float* __restrict__ beta,
                                                const float* __restrict__ mean,
                                                const float* __restrict__ var,
                                                const float* __restrict__ w2,
                                                const float* __restrict__ b2,
                                                float* __restrict__ thres) {
    __shared__ float s_avg[ROWS_];
    __shared__ float s_h[B_ * MIP_];   // 256
    const int t = threadIdx.x;
    for (int i = t; i < ROWS_; i += 256) s_avg[i] = avg[i];
    __syncthreads();
    // h[b][m]: 8*32 = 256 dot products of length C_=128, one per thread
    {
        const int b = t >> 5, m = t & 31;
        float acc = b1[m];
        const float* wrow = w1 + m * C_;
        const float* arow = s_avg + b * C_;
        #pragma unroll 8
        for (int c = 0; c < C_; ++c) acc = fmaf(wrow[c], arow[c], acc);
        acc = (acc - mean[m]) * rsqrtf(var[m] + BN_EPS_);
        acc = fmaf(acc, gamma[m], beta[m]);
        s_h[t] = fmaxf(acc, 0.0f);
    }
    __syncthreads();
    // g[b][c] -> thres: 1024 outputs, 4 per thread, dot length MIP_=32
    for (int i = t; i < ROWS_; i += 256) {
        const int b = i >> 7, c = i & 127;
        float acc = b2[c];
        const float* wrow = w2 + c * MIP_;
        const float* hrow = s_h + b * MIP_;
        #pragma unroll
        for (int m = 0; m < MIP_; ++m) acc = fmaf(wrow[m], hrow[m], acc);
        float g = fminf(fmaxf((acc + 3.0f) * (1.0f / 6.0f), 0.0f), 1.0f);
        thres[i] = s_avg[i] * g;
    }
}

// ---------------------------------------------------------------------------
// Kernel 3: elementwise soft-threshold. Grid-stride float4.
// ---------------------------------------------------------------------------
__global__ __launch_bounds__(256) void shrink(const float4* __restrict__ x4,
                                              const float* __restrict__ thres,
                                              const float* __restrict__ a,
                                              float4* __restrict__ out4,
                                              int n4) {
    const float oma = 1.0f - a[0];
    const int stride = gridDim.x * blockDim.x;
    for (int i = blockIdx.x * blockDim.x + threadIdx.x; i < n4; i += stride) {
        const float t = thres[i >> 14];         // L4_ = 16384 float4s per row
        float4 v = x4[i];
        float4 o;
        {
            float sub = fmaxf(fabsf(v.x) - t, 0.0f);
            float sgn = (v.x > 0.0f) ? 1.0f : ((v.x < 0.0f) ? -1.0f : 0.0f);
            o.x = (sub > 0.0f) ? sgn * (sub + oma * t) : 0.0f;
        }
        {
            float sub = fmaxf(fabsf(v.y) - t, 0.0f);
            float sgn = (v.y > 0.0f) ? 1.0f : ((v.y < 0.0f) ? -1.0f : 0.0f);
            o.y = (sub > 0.0f) ? sgn * (sub + oma * t) : 0.0f;
        }
        {
            float sub = fmaxf(fabsf(v.z) - t, 0.0f);
            float sgn = (v.z > 0.0f) ? 1.0f : ((v.z < 0.0f) ? -1.0f : 0.0f);
            o.z = (sub > 0.0f) ? sgn * (sub + oma * t) : 0.0f;
        }
        {
            float sub = fmaxf(fabsf(v.w) - t, 0.0f);
            float sgn = (v.w > 0.0f) ? 1.0f : ((v.w < 0.0f) ? -1.0f : 0.0f);
            o.w = (sub > 0.0f) ? sgn * (sub + oma * t) : 0.0f;
        }
        out4[i] = o;
    }
}

extern "C" void kernel_launch(void* const* d_in, const int* in_sizes, int n_in,
                              void* d_out, int out_size, void* d_ws, size_t ws_size,
                              hipStream_t stream) {
    // setup_inputs order: x, a, w1, b1, bn_gamma, bn_beta, bn_mean, bn_var, w2, b2
    const float* x     = (const float*)d_in[0];
    const float* a     = (const float*)d_in[1];
    const float* w1    = (const float*)d_in[2];
    const float* b1    = (const float*)d_in[3];
    const float* gamma = (const float*)d_in[4];
    const float* beta  = (const float*)d_in[5];
    const float* mean  = (const float*)d_in[6];
    const float* var   = (const float*)d_in[7];
    const float* w2    = (const float*)d_in[8];
    const float* b2    = (const float*)d_in[9];
    float* out = (float*)d_out;

    float* avg   = (float*)d_ws;            // ROWS_ floats
    float* thres = avg + ROWS_;             // ROWS_ floats

    reduce_rows<<<ROWS_, 256, 0, stream>>>(x, avg);
    fc_thres<<<1, 256, 0, stream>>>(avg, w1, b1, gamma, beta, mean, var, w2, b2, thres);

    const int n4 = (B_ * C_ * L_) / 4;      // 16,777,216
    shrink<<<2048, 256, 0, stream>>>((const float4*)x, thres, a, (float4*)out, n4);
}